// Round 1
// baseline (153.796 us; speedup 1.0000x reference)
//
#include <hip/hip_runtime.h>
#include <math.h>

#define B 64
#define N 4096
#define K 819            // int(4096 * 0.2)
#define EPSF 1e-8f
#define TRADE_LAMBDA 0.25f

// ws layout (floats):
//   s_top  [B][K]
//   w_top  [B][K]   (sqrt of weights)
//   s_bot  [B][K]
//   w_bot  [B][K]   (sqrt of weights)
//   rank_num  [B]
//   sum_swt   [B]
//   sum_swb   [B]
//   trade_num [B]
//   trade_wsum[B]
//   p_sum     [B]
#define OFF_STOP 0
#define OFF_WTOP (B*K)
#define OFF_SBOT (2*B*K)
#define OFF_WBOT (3*B*K)
#define OFF_RNUM (4*B*K)
#define OFF_SWT  (4*B*K + B)
#define OFF_SWB  (4*B*K + 2*B)
#define OFF_TNUM (4*B*K + 3*B)
#define OFF_TWS  (4*B*K + 4*B)
#define OFF_PSUM (4*B*K + 5*B)

__device__ __forceinline__ unsigned f2key(float f) {
    unsigned u = __float_as_uint(f);
    return (u & 0x80000000u) ? ~u : (u | 0x80000000u);
}

__device__ __forceinline__ float softplusf(float x) {
    // log(1 + exp(x)), numerically stable
    float ax = fabsf(x);
    return fmaxf(x, 0.f) + __logf(1.f + __expf(-ax));
}

// One block per batch row. 1024 threads.
// 1) trade-loss partial sums  2) bitonic sort of y_rank keys (LDS)
// 3) threshold + exact-count gather of top-k / bottom-k scores & sqrt-weights
__global__ __launch_bounds__(1024) void k_sort_gather(
    const float* __restrict__ scores, const float* __restrict__ p_trade,
    const float* __restrict__ y_rank, const float* __restrict__ y_trade,
    const float* __restrict__ weights, const float* __restrict__ mask,
    float* __restrict__ ws)
{
    __shared__ unsigned keys[N];
    __shared__ float red[48];
    __shared__ int cnts[8];

    const int b = blockIdx.x;
    const int tid = threadIdx.x;
    const float* yr = y_rank  + b * N;
    const float* sc = scores  + b * N;
    const float* wt = weights + b * N;
    const float* pt = p_trade + b * N;
    const float* yt = y_trade + b * N;
    const float* mk = mask    + b * N;

    // ---- pass 1: load keys into LDS + trade-loss partials ----
    float s_wsum = 0.f, s_tnum = 0.f, s_ps = 0.f;
    for (int i = tid; i < N; i += 1024) {
        keys[i] = f2key(yr[i]);
        float p = pt[i], ytr = yt[i], w = wt[i], m = mk[i];
        float mw = w * m;
        float bce = -(ytr * __logf(p) + (1.f - ytr) * __logf(1.f - p));
        s_wsum += mw;
        s_tnum = fmaf(bce, mw, s_tnum);
        s_ps += p;
    }
    #pragma unroll
    for (int o = 32; o > 0; o >>= 1) {
        s_wsum += __shfl_down(s_wsum, o, 64);
        s_tnum += __shfl_down(s_tnum, o, 64);
        s_ps   += __shfl_down(s_ps,   o, 64);
    }
    {
        int wv = tid >> 6;
        if ((tid & 63) == 0) { red[wv] = s_wsum; red[16 + wv] = s_tnum; red[32 + wv] = s_ps; }
    }
    __syncthreads();
    if (tid == 0) {
        float a = 0.f, bb = 0.f, c = 0.f;
        for (int w = 0; w < 16; w++) { a += red[w]; bb += red[16 + w]; c += red[32 + w]; }
        ws[OFF_TWS  + b] = a;
        ws[OFF_TNUM + b] = bb;
        ws[OFF_PSUM + b] = c;
        ws[OFF_RNUM + b] = 0.f;  // zero accumulator for k_pair
    }

    // ---- pass 2: bitonic sort (ascending) of keys in LDS ----
    for (unsigned size = 2; size <= N; size <<= 1) {
        for (unsigned stride = size >> 1; stride > 0; stride >>= 1) {
            __syncthreads();
            for (unsigned t = tid; t < N; t += 1024) {
                unsigned partner = t ^ stride;
                if (partner > t) {
                    unsigned a = keys[t], c = keys[partner];
                    bool up = ((t & size) == 0);
                    if ((a > c) == up) { keys[t] = c; keys[partner] = a; }
                }
            }
        }
    }
    __syncthreads();
    const unsigned t_top = keys[N - K];  // k-th largest
    const unsigned t_bot = keys[K - 1];  // k-th smallest
    if (tid < 8) cnts[tid] = 0;
    __syncthreads();

    // ---- pass 3: count strict-side elements ----
    unsigned mykeys[4];
    int my_gt = 0, my_lt = 0;
    #pragma unroll
    for (int c = 0; c < 4; c++) {
        int i = tid + c * 1024;
        unsigned kk = f2key(yr[i]);
        mykeys[c] = kk;
        my_gt += (kk > t_top);
        my_lt += (kk < t_bot);
    }
    if (my_gt) atomicAdd(&cnts[0], my_gt);
    if (my_lt) atomicAdd(&cnts[1], my_lt);
    __syncthreads();
    const int c1t = cnts[0];
    const int c1b = cnts[1];

    // ---- pass 4: gather top-k / bottom-k (exact, tie-aware) ----
    float* s_top = ws + OFF_STOP + b * K;
    float* w_top = ws + OFF_WTOP + b * K;
    float* s_bot = ws + OFF_SBOT + b * K;
    float* w_bot = ws + OFF_WBOT + b * K;
    float swt = 0.f, swb = 0.f;
    #pragma unroll
    for (int c = 0; c < 4; c++) {
        int i = tid + c * 1024;
        unsigned kk = mykeys[c];
        if (kk > t_top) {
            int pos = atomicAdd(&cnts[2], 1);
            float sw = sqrtf(wt[i]);
            s_top[pos] = sc[i]; w_top[pos] = sw; swt += sw;
        } else if (kk == t_top) {
            int tt = atomicAdd(&cnts[3], 1);
            if (tt < K - c1t) {
                int pos = c1t + tt;
                float sw = sqrtf(wt[i]);
                s_top[pos] = sc[i]; w_top[pos] = sw; swt += sw;
            }
        }
        if (kk < t_bot) {
            int pos = atomicAdd(&cnts[4], 1);
            float sw = sqrtf(wt[i]);
            s_bot[pos] = sc[i]; w_bot[pos] = sw; swb += sw;
        } else if (kk == t_bot) {
            int tt = atomicAdd(&cnts[5], 1);
            if (tt < K - c1b) {
                int pos = c1b + tt;
                float sw = sqrtf(wt[i]);
                s_bot[pos] = sc[i]; w_bot[pos] = sw; swb += sw;
            }
        }
    }
    // reduce sqrt-weight sums
    #pragma unroll
    for (int o = 32; o > 0; o >>= 1) {
        swt += __shfl_down(swt, o, 64);
        swb += __shfl_down(swb, o, 64);
    }
    __syncthreads();
    {
        int wv = tid >> 6;
        if ((tid & 63) == 0) { red[wv] = swt; red[16 + wv] = swb; }
    }
    __syncthreads();
    if (tid == 0) {
        float a = 0.f, bb = 0.f;
        for (int w = 0; w < 16; w++) { a += red[w]; bb += red[16 + w]; }
        ws[OFF_SWT + b] = a;
        ws[OFF_SWB + b] = bb;
    }
}

// Pairwise softplus reduction. grid = (B, 4 i-tiles, 2 j-halves), block = 256.
__global__ __launch_bounds__(256) void k_pair(float* __restrict__ ws)
{
    __shared__ __align__(16) float sb[416];
    __shared__ __align__(16) float wb[416];
    __shared__ float red2[4];

    const int b = blockIdx.x;
    const int it = blockIdx.y;   // i tile
    const int z  = blockIdx.z;   // j half
    const int tid = threadIdx.x;

    const float* s_top = ws + OFF_STOP + b * K;
    const float* w_top = ws + OFF_WTOP + b * K;
    const float* s_bot = ws + OFF_SBOT + b * K;
    const float* w_bot = ws + OFF_WBOT + b * K;

    const int jbase = (z == 0) ? 0 : 412;
    const int jlen  = (z == 0) ? 412 : 407;
    const int jpad  = (jlen + 3) & ~3;

    for (int jj = tid; jj < jpad; jj += 256) {
        if (jj < jlen) { sb[jj] = s_bot[jbase + jj]; wb[jj] = w_bot[jbase + jj]; }
        else           { sb[jj] = 0.f;               wb[jj] = 0.f; }
    }
    __syncthreads();

    const int i = it * 256 + tid;
    const bool valid = (i < K);
    const float si = valid ? s_top[i] : 0.f;
    const float wi = valid ? w_top[i] : 0.f;

    float acc = 0.f;
    const float4* sv = (const float4*)sb;
    const float4* wv = (const float4*)wb;
    const int nq = jpad >> 2;
    for (int q = 0; q < nq; q++) {
        float4 s4 = sv[q];
        float4 w4 = wv[q];
        acc = fmaf(softplusf(s4.x - si), w4.x, acc);
        acc = fmaf(softplusf(s4.y - si), w4.y, acc);
        acc = fmaf(softplusf(s4.z - si), w4.z, acc);
        acc = fmaf(softplusf(s4.w - si), w4.w, acc);
    }
    float contrib = acc * wi;

    #pragma unroll
    for (int o = 32; o > 0; o >>= 1) contrib += __shfl_down(contrib, o, 64);
    if ((tid & 63) == 0) red2[tid >> 6] = contrib;
    __syncthreads();
    if (tid == 0) {
        float tot = red2[0] + red2[1] + red2[2] + red2[3];
        atomicAdd(&ws[OFF_RNUM + b], tot);
    }
}

// Finalize: one wave handles all 64 batches.
__global__ __launch_bounds__(64) void k_final(const float* __restrict__ ws,
                                              float* __restrict__ out)
{
    const int t = threadIdx.x;  // 0..63 == batch
    float rn  = ws[OFF_RNUM + t];
    float st  = ws[OFF_SWT  + t];
    float sbm = ws[OFF_SWB  + t];
    float lr  = rn / (st * sbm + EPSF);

    float wsum = ws[OFF_TWS  + t];
    float pbt  = ws[OFF_TNUM + t] / (wsum + EPSF);
    float vld  = (wsum > 0.f) ? 1.f : 0.f;
    float vtr  = vld * pbt;
    float ps   = ws[OFF_PSUM + t];

    #pragma unroll
    for (int o = 32; o > 0; o >>= 1) {
        lr  += __shfl_down(lr,  o, 64);
        vtr += __shfl_down(vtr, o, 64);
        vld += __shfl_down(vld, o, 64);
        ps  += __shfl_down(ps,  o, 64);
    }
    if (t == 0) {
        float avg_rank  = lr / (float)B;
        float nv        = fmaxf(vld, 1.f);
        float avg_trade = vtr / nv;
        float mean_p    = ps / (float)(B * N);
        out[0] = avg_rank + TRADE_LAMBDA * avg_trade;
        out[1] = avg_rank;
        out[2] = avg_trade;
        out[3] = mean_p;
    }
}

extern "C" void kernel_launch(void* const* d_in, const int* in_sizes, int n_in,
                              void* d_out, int out_size, void* d_ws, size_t ws_size,
                              hipStream_t stream) {
    const float* scores  = (const float*)d_in[0];
    const float* p_trade = (const float*)d_in[1];
    const float* y_rank  = (const float*)d_in[2];
    const float* y_trade = (const float*)d_in[3];
    const float* weights = (const float*)d_in[4];
    const float* mask    = (const float*)d_in[5];
    float* ws  = (float*)d_ws;
    float* out = (float*)d_out;

    hipLaunchKernelGGL(k_sort_gather, dim3(B), dim3(1024), 0, stream,
                       scores, p_trade, y_rank, y_trade, weights, mask, ws);
    hipLaunchKernelGGL(k_pair, dim3(B, 4, 2), dim3(256), 0, stream, ws);
    hipLaunchKernelGGL(k_final, dim3(1), dim3(64), 0, stream, ws, out);
}

// Round 2
// 113.306 us; speedup vs baseline: 1.3574x; 1.3574x over previous
//
#include <hip/hip_runtime.h>
#include <math.h>

#define B 64
#define N 4096
#define K 819            // int(4096 * 0.2)
#define EPSF 1e-8f
#define TRADE_LAMBDA 0.25f

// ws layout (floats):
//   s_top[B][K], w_top[B][K] (sqrt w), s_bot[B][K], w_bot[B][K],
//   rank_num[B], sum_swt[B], sum_swb[B], trade_num[B], trade_wsum[B], p_sum[B]
#define OFF_STOP 0
#define OFF_WTOP (B*K)
#define OFF_SBOT (2*B*K)
#define OFF_WBOT (3*B*K)
#define OFF_RNUM (4*B*K)
#define OFF_SWT  (4*B*K + B)
#define OFF_SWB  (4*B*K + 2*B)
#define OFF_TNUM (4*B*K + 3*B)
#define OFF_TWS  (4*B*K + 4*B)
#define OFF_PSUM (4*B*K + 5*B)

__device__ __forceinline__ unsigned f2key(float f) {
    unsigned u = __float_as_uint(f);
    return (u & 0x80000000u) ? ~u : (u | 0x80000000u);
}

__device__ __forceinline__ float softplusf(float x) {
    float ax = fabsf(x);
    return fmaxf(x, 0.f) + __logf(1.f + __expf(-ax));
}

// One block per batch row, 1024 threads.
// 1) trade-loss partials + keys into registers
// 2) 4-pass byte-radix select for K-th largest (t_top) and K-th smallest (t_bot)
// 3) exact-count tie-aware gather of top-k / bottom-k scores & sqrt-weights
__global__ __launch_bounds__(1024) void k_select(
    const float* __restrict__ scores, const float* __restrict__ p_trade,
    const float* __restrict__ y_rank, const float* __restrict__ y_trade,
    const float* __restrict__ weights, const float* __restrict__ mask,
    float* __restrict__ ws)
{
    __shared__ int hist_t[256];
    __shared__ int hist_b[256];
    __shared__ int found_t[2];   // [bin, excl_count]
    __shared__ int found_b[2];
    __shared__ float red[48];
    __shared__ int cnts[8];

    const int b = blockIdx.x;
    const int tid = threadIdx.x;
    const float* yr = y_rank  + b * N;
    const float* sc = scores  + b * N;
    const float* wt = weights + b * N;
    const float* pt = p_trade + b * N;
    const float* yt = y_trade + b * N;
    const float* mk = mask    + b * N;

    // ---- pass 1: keys into registers + trade-loss partials ----
    unsigned mykeys[4];
    float s_wsum = 0.f, s_tnum = 0.f, s_ps = 0.f;
    #pragma unroll
    for (int c = 0; c < 4; c++) {
        int i = tid + c * 1024;
        mykeys[c] = f2key(yr[i]);
        float p = pt[i], ytr = yt[i], w = wt[i], m = mk[i];
        float mw = w * m;
        float bce = -(ytr * __logf(p) + (1.f - ytr) * __logf(1.f - p));
        s_wsum += mw;
        s_tnum = fmaf(bce, mw, s_tnum);
        s_ps += p;
    }
    #pragma unroll
    for (int o = 32; o > 0; o >>= 1) {
        s_wsum += __shfl_down(s_wsum, o, 64);
        s_tnum += __shfl_down(s_tnum, o, 64);
        s_ps   += __shfl_down(s_ps,   o, 64);
    }
    {
        int wv = tid >> 6;
        if ((tid & 63) == 0) { red[wv] = s_wsum; red[16 + wv] = s_tnum; red[32 + wv] = s_ps; }
    }
    __syncthreads();
    if (tid == 0) {
        float a = 0.f, bb = 0.f, c = 0.f;
        for (int w = 0; w < 16; w++) { a += red[w]; bb += red[16 + w]; c += red[32 + w]; }
        ws[OFF_TWS  + b] = a;
        ws[OFF_TNUM + b] = bb;
        ws[OFF_PSUM + b] = c;
        ws[OFF_RNUM + b] = 0.f;  // zero accumulator for k_pair
    }

    // ---- pass 2: radix select (MSB->LSB bytes) ----
    unsigned pfx_t = 0u, pfx_b = 0u, msk = 0u;
    int rem_t = K, rem_b = K;
    #pragma unroll
    for (int pass = 0; pass < 4; pass++) {
        const int shift = 24 - 8 * pass;
        // zero histograms
        if (tid < 256) hist_t[tid] = 0;
        else if (tid < 512) hist_b[tid - 256] = 0;
        __syncthreads();
        // accumulate (keys in registers; only prefix-matching candidates)
        #pragma unroll
        for (int c = 0; c < 4; c++) {
            unsigned kk = mykeys[c];
            if ((kk & msk) == pfx_t) atomicAdd(&hist_t[(kk >> shift) & 0xFF], 1);
            if ((kk & msk) == pfx_b) atomicAdd(&hist_b[(kk >> shift) & 0xFF], 1);
        }
        __syncthreads();
        // wave 0: suffix scan for top (K-th largest); wave 1: prefix scan for bottom
        if (tid < 64) {
            int base = tid * 4;
            int c0 = hist_t[base], c1 = hist_t[base + 1], c2 = hist_t[base + 2], c3 = hist_t[base + 3];
            int lane_sum = c0 + c1 + c2 + c3;
            int s = lane_sum;
            #pragma unroll
            for (int o = 1; o < 64; o <<= 1) {
                int v = __shfl_down(s, o, 64);
                if (tid + o < 64) s += v;
            }
            int above = s - lane_sum;          // sum over lanes > tid
            int se3 = above;
            int se2 = se3 + c3;
            int se1 = se2 + c2;
            int se0 = se1 + c1;
            if (se0 < rem_t && rem_t <= se0 + c0) { found_t[0] = base + 0; found_t[1] = se0; }
            if (se1 < rem_t && rem_t <= se1 + c1) { found_t[0] = base + 1; found_t[1] = se1; }
            if (se2 < rem_t && rem_t <= se2 + c2) { found_t[0] = base + 2; found_t[1] = se2; }
            if (se3 < rem_t && rem_t <= se3 + c3) { found_t[0] = base + 3; found_t[1] = se3; }
        } else if (tid < 128) {
            int l = tid - 64;
            int base = l * 4;
            int c0 = hist_b[base], c1 = hist_b[base + 1], c2 = hist_b[base + 2], c3 = hist_b[base + 3];
            int lane_sum = c0 + c1 + c2 + c3;
            int s = lane_sum;
            #pragma unroll
            for (int o = 1; o < 64; o <<= 1) {
                int v = __shfl_up(s, o, 64);
                if (l - o >= 0) s += v;
            }
            int below = s - lane_sum;          // sum over lanes < l
            int pe0 = below;
            int pe1 = pe0 + c0;
            int pe2 = pe1 + c1;
            int pe3 = pe2 + c2;
            if (pe0 < rem_b && rem_b <= pe0 + c0) { found_b[0] = base + 0; found_b[1] = pe0; }
            if (pe1 < rem_b && rem_b <= pe1 + c1) { found_b[0] = base + 1; found_b[1] = pe1; }
            if (pe2 < rem_b && rem_b <= pe2 + c2) { found_b[0] = base + 2; found_b[1] = pe2; }
            if (pe3 < rem_b && rem_b <= pe3 + c3) { found_b[0] = base + 3; found_b[1] = pe3; }
        }
        __syncthreads();
        pfx_t |= ((unsigned)found_t[0]) << shift;
        rem_t -= found_t[1];
        pfx_b |= ((unsigned)found_b[0]) << shift;
        rem_b -= found_b[1];
        msk |= 0xFFu << shift;
    }
    const unsigned t_top = pfx_t;  // exact K-th largest key
    const unsigned t_bot = pfx_b;  // exact K-th smallest key

    if (tid < 8) cnts[tid] = 0;
    __syncthreads();

    // ---- pass 3: count strict-side elements ----
    int my_gt = 0, my_lt = 0;
    #pragma unroll
    for (int c = 0; c < 4; c++) {
        unsigned kk = mykeys[c];
        my_gt += (kk > t_top);
        my_lt += (kk < t_bot);
    }
    if (my_gt) atomicAdd(&cnts[0], my_gt);
    if (my_lt) atomicAdd(&cnts[1], my_lt);
    __syncthreads();
    const int c1t = cnts[0];
    const int c1b = cnts[1];

    // ---- pass 4: gather top-k / bottom-k (exact, tie-aware) ----
    float* s_top = ws + OFF_STOP + b * K;
    float* w_top = ws + OFF_WTOP + b * K;
    float* s_bot = ws + OFF_SBOT + b * K;
    float* w_bot = ws + OFF_WBOT + b * K;
    float swt = 0.f, swb = 0.f;
    #pragma unroll
    for (int c = 0; c < 4; c++) {
        int i = tid + c * 1024;
        unsigned kk = mykeys[c];
        if (kk > t_top) {
            int pos = atomicAdd(&cnts[2], 1);
            float sw = sqrtf(wt[i]);
            s_top[pos] = sc[i]; w_top[pos] = sw; swt += sw;
        } else if (kk == t_top) {
            int tt = atomicAdd(&cnts[3], 1);
            if (tt < K - c1t) {
                int pos = c1t + tt;
                float sw = sqrtf(wt[i]);
                s_top[pos] = sc[i]; w_top[pos] = sw; swt += sw;
            }
        }
        if (kk < t_bot) {
            int pos = atomicAdd(&cnts[4], 1);
            float sw = sqrtf(wt[i]);
            s_bot[pos] = sc[i]; w_bot[pos] = sw; swb += sw;
        } else if (kk == t_bot) {
            int tt = atomicAdd(&cnts[5], 1);
            if (tt < K - c1b) {
                int pos = c1b + tt;
                float sw = sqrtf(wt[i]);
                s_bot[pos] = sc[i]; w_bot[pos] = sw; swb += sw;
            }
        }
    }
    #pragma unroll
    for (int o = 32; o > 0; o >>= 1) {
        swt += __shfl_down(swt, o, 64);
        swb += __shfl_down(swb, o, 64);
    }
    __syncthreads();
    {
        int wv = tid >> 6;
        if ((tid & 63) == 0) { red[wv] = swt; red[16 + wv] = swb; }
    }
    __syncthreads();
    if (tid == 0) {
        float a = 0.f, bb = 0.f;
        for (int w = 0; w < 16; w++) { a += red[w]; bb += red[16 + w]; }
        ws[OFF_SWT + b] = a;
        ws[OFF_SWB + b] = bb;
    }
}

// Pairwise softplus reduction. grid = (B, 4 i-tiles, 4 j-chunks), block = 256.
__global__ __launch_bounds__(256) void k_pair(float* __restrict__ ws)
{
    __shared__ __align__(16) float sb[208];
    __shared__ __align__(16) float wb[208];
    __shared__ float red2[4];

    const int b = blockIdx.x;
    const int it = blockIdx.y;   // i tile
    const int z  = blockIdx.z;   // j chunk
    const int tid = threadIdx.x;

    const float* s_top = ws + OFF_STOP + b * K;
    const float* w_top = ws + OFF_WTOP + b * K;
    const float* s_bot = ws + OFF_SBOT + b * K;
    const float* w_bot = ws + OFF_WBOT + b * K;

    const int jbase = z * 205;
    const int jlen  = (z == 3) ? (K - 3 * 205) : 205;   // 204 for z==3
    const int jpad  = 208;

    for (int jj = tid; jj < jpad; jj += 256) {
        if (jj < jlen) { sb[jj] = s_bot[jbase + jj]; wb[jj] = w_bot[jbase + jj]; }
        else           { sb[jj] = 0.f;               wb[jj] = 0.f; }
    }
    __syncthreads();

    const int i = it * 256 + tid;
    const bool valid = (i < K);
    const float si = valid ? s_top[i] : 0.f;
    const float wi = valid ? w_top[i] : 0.f;

    float acc = 0.f;
    const float4* sv = (const float4*)sb;
    const float4* wv = (const float4*)wb;
    for (int q = 0; q < 52; q++) {
        float4 s4 = sv[q];
        float4 w4 = wv[q];
        acc = fmaf(softplusf(s4.x - si), w4.x, acc);
        acc = fmaf(softplusf(s4.y - si), w4.y, acc);
        acc = fmaf(softplusf(s4.z - si), w4.z, acc);
        acc = fmaf(softplusf(s4.w - si), w4.w, acc);
    }
    float contrib = acc * wi;

    #pragma unroll
    for (int o = 32; o > 0; o >>= 1) contrib += __shfl_down(contrib, o, 64);
    if ((tid & 63) == 0) red2[tid >> 6] = contrib;
    __syncthreads();
    if (tid == 0) {
        float tot = red2[0] + red2[1] + red2[2] + red2[3];
        atomicAdd(&ws[OFF_RNUM + b], tot);
    }
}

// Finalize: one wave handles all 64 batches.
__global__ __launch_bounds__(64) void k_final(const float* __restrict__ ws,
                                              float* __restrict__ out)
{
    const int t = threadIdx.x;  // 0..63 == batch
    float rn  = ws[OFF_RNUM + t];
    float st  = ws[OFF_SWT  + t];
    float sbm = ws[OFF_SWB  + t];
    float lr  = rn / (st * sbm + EPSF);

    float wsum = ws[OFF_TWS  + t];
    float pbt  = ws[OFF_TNUM + t] / (wsum + EPSF);
    float vld  = (wsum > 0.f) ? 1.f : 0.f;
    float vtr  = vld * pbt;
    float ps   = ws[OFF_PSUM + t];

    #pragma unroll
    for (int o = 32; o > 0; o >>= 1) {
        lr  += __shfl_down(lr,  o, 64);
        vtr += __shfl_down(vtr, o, 64);
        vld += __shfl_down(vld, o, 64);
        ps  += __shfl_down(ps,  o, 64);
    }
    if (t == 0) {
        float avg_rank  = lr / (float)B;
        float nv        = fmaxf(vld, 1.f);
        float avg_trade = vtr / nv;
        float mean_p    = ps / (float)(B * N);
        out[0] = avg_rank + TRADE_LAMBDA * avg_trade;
        out[1] = avg_rank;
        out[2] = avg_trade;
        out[3] = mean_p;
    }
}

extern "C" void kernel_launch(void* const* d_in, const int* in_sizes, int n_in,
                              void* d_out, int out_size, void* d_ws, size_t ws_size,
                              hipStream_t stream) {
    const float* scores  = (const float*)d_in[0];
    const float* p_trade = (const float*)d_in[1];
    const float* y_rank  = (const float*)d_in[2];
    const float* y_trade = (const float*)d_in[3];
    const float* weights = (const float*)d_in[4];
    const float* mask    = (const float*)d_in[5];
    float* ws  = (float*)d_ws;
    float* out = (float*)d_out;

    hipLaunchKernelGGL(k_select, dim3(B), dim3(1024), 0, stream,
                       scores, p_trade, y_rank, y_trade, weights, mask, ws);
    hipLaunchKernelGGL(k_pair, dim3(B, 4, 4), dim3(256), 0, stream, ws);
    hipLaunchKernelGGL(k_final, dim3(1), dim3(64), 0, stream, ws, out);
}

// Round 3
// 112.744 us; speedup vs baseline: 1.3641x; 1.0050x over previous
//
#include <hip/hip_runtime.h>
#include <math.h>

#define B 64
#define N 4096
#define K 819            // int(4096 * 0.2)
#define EPSF 1e-8f
#define TRADE_LAMBDA 0.25f

// ws layout (floats):
//   s_top[B][K], w_top[B][K] (sqrt w), s_bot[B][K], w_bot[B][K],
//   rank_num[B], sum_swt[B], sum_swb[B], trade_num[B], trade_wsum[B], p_sum[B]
#define OFF_STOP 0
#define OFF_WTOP (B*K)
#define OFF_SBOT (2*B*K)
#define OFF_WBOT (3*B*K)
#define OFF_RNUM (4*B*K)
#define OFF_SWT  (4*B*K + B)
#define OFF_SWB  (4*B*K + 2*B)
#define OFF_TNUM (4*B*K + 3*B)
#define OFF_TWS  (4*B*K + 4*B)
#define OFF_PSUM (4*B*K + 5*B)

__device__ __forceinline__ unsigned f2key(float f) {
    unsigned u = __float_as_uint(f);
    return (u & 0x80000000u) ? ~u : (u | 0x80000000u);
}

__device__ __forceinline__ float softplusf(float x) {
    float ax = fabsf(x);
    return fmaxf(x, 0.f) + __logf(1.f + __expf(-ax));
}

// Heterogeneous grid of 128 blocks x 1024 threads:
//   blocks 0..63   : radix-select top-K / bottom-K of y_rank row b, gather
//                    scores & sqrt-weights into ws (keys+payload in registers)
//   blocks 64..127 : trade-loss (BCE) row sums for row b-64
__global__ __launch_bounds__(1024) void k_select_trade(
    const float* __restrict__ scores, const float* __restrict__ p_trade,
    const float* __restrict__ y_rank, const float* __restrict__ y_trade,
    const float* __restrict__ weights, const float* __restrict__ mask,
    float* __restrict__ ws)
{
    __shared__ int hist_t[256];
    __shared__ int hist_b[256];
    __shared__ int found_t[2];   // [bin, excl_count]
    __shared__ int found_b[2];
    __shared__ float red[48];
    __shared__ int cnts[8];

    const int tid = threadIdx.x;

    if (blockIdx.x >= 64) {
        // ================= trade role =================
        const int b = blockIdx.x - 64;
        const float* wt = weights + b * N;
        const float* pt = p_trade + b * N;
        const float* yt = y_trade + b * N;
        const float* mk = mask    + b * N;
        float s_wsum = 0.f, s_tnum = 0.f, s_ps = 0.f;
        #pragma unroll
        for (int c = 0; c < 4; c++) {
            int i = tid + c * 1024;
            float p = pt[i], ytr = yt[i], w = wt[i], m = mk[i];
            float mw = w * m;
            float bce = -(ytr * __logf(p) + (1.f - ytr) * __logf(1.f - p));
            s_wsum += mw;
            s_tnum = fmaf(bce, mw, s_tnum);
            s_ps += p;
        }
        #pragma unroll
        for (int o = 32; o > 0; o >>= 1) {
            s_wsum += __shfl_down(s_wsum, o, 64);
            s_tnum += __shfl_down(s_tnum, o, 64);
            s_ps   += __shfl_down(s_ps,   o, 64);
        }
        int wv = tid >> 6;
        if ((tid & 63) == 0) { red[wv] = s_wsum; red[16 + wv] = s_tnum; red[32 + wv] = s_ps; }
        __syncthreads();
        if (tid == 0) {
            float a = 0.f, bb = 0.f, c = 0.f;
            for (int w = 0; w < 16; w++) { a += red[w]; bb += red[16 + w]; c += red[32 + w]; }
            ws[OFF_TWS  + b] = a;
            ws[OFF_TNUM + b] = bb;
            ws[OFF_PSUM + b] = c;
            ws[OFF_RNUM + b] = 0.f;  // zero accumulator for k_pair
        }
        return;
    }

    // ================= select role =================
    const int b = blockIdx.x;
    const float* yr = y_rank  + b * N;
    const float* sc = scores  + b * N;
    const float* wt = weights + b * N;

    // ---- pass 1: keys + payload into registers (coalesced) ----
    unsigned mykeys[4];
    float mysc[4], mysw[4];
    #pragma unroll
    for (int c = 0; c < 4; c++) {
        int i = tid + c * 1024;
        mykeys[c] = f2key(yr[i]);
        mysc[c] = sc[i];
        mysw[c] = sqrtf(wt[i]);
    }

    // ---- pass 2: radix select (MSB->LSB bytes) ----
    unsigned pfx_t = 0u, pfx_b = 0u, msk = 0u;
    int rem_t = K, rem_b = K;
    #pragma unroll
    for (int pass = 0; pass < 4; pass++) {
        const int shift = 24 - 8 * pass;
        if (tid < 256) hist_t[tid] = 0;
        else if (tid < 512) hist_b[tid - 256] = 0;
        __syncthreads();
        #pragma unroll
        for (int c = 0; c < 4; c++) {
            unsigned kk = mykeys[c];
            if ((kk & msk) == pfx_t) atomicAdd(&hist_t[(kk >> shift) & 0xFF], 1);
            if ((kk & msk) == pfx_b) atomicAdd(&hist_b[(kk >> shift) & 0xFF], 1);
        }
        __syncthreads();
        if (tid < 64) {
            int base = tid * 4;
            int c0 = hist_t[base], c1 = hist_t[base + 1], c2 = hist_t[base + 2], c3 = hist_t[base + 3];
            int lane_sum = c0 + c1 + c2 + c3;
            int s = lane_sum;
            #pragma unroll
            for (int o = 1; o < 64; o <<= 1) {
                int v = __shfl_down(s, o, 64);
                if (tid + o < 64) s += v;
            }
            int above = s - lane_sum;          // sum over lanes > tid
            int se3 = above;
            int se2 = se3 + c3;
            int se1 = se2 + c2;
            int se0 = se1 + c1;
            if (se0 < rem_t && rem_t <= se0 + c0) { found_t[0] = base + 0; found_t[1] = se0; }
            if (se1 < rem_t && rem_t <= se1 + c1) { found_t[0] = base + 1; found_t[1] = se1; }
            if (se2 < rem_t && rem_t <= se2 + c2) { found_t[0] = base + 2; found_t[1] = se2; }
            if (se3 < rem_t && rem_t <= se3 + c3) { found_t[0] = base + 3; found_t[1] = se3; }
        } else if (tid < 128) {
            int l = tid - 64;
            int base = l * 4;
            int c0 = hist_b[base], c1 = hist_b[base + 1], c2 = hist_b[base + 2], c3 = hist_b[base + 3];
            int lane_sum = c0 + c1 + c2 + c3;
            int s = lane_sum;
            #pragma unroll
            for (int o = 1; o < 64; o <<= 1) {
                int v = __shfl_up(s, o, 64);
                if (l - o >= 0) s += v;
            }
            int below = s - lane_sum;          // sum over lanes < l
            int pe0 = below;
            int pe1 = pe0 + c0;
            int pe2 = pe1 + c1;
            int pe3 = pe2 + c2;
            if (pe0 < rem_b && rem_b <= pe0 + c0) { found_b[0] = base + 0; found_b[1] = pe0; }
            if (pe1 < rem_b && rem_b <= pe1 + c1) { found_b[0] = base + 1; found_b[1] = pe1; }
            if (pe2 < rem_b && rem_b <= pe2 + c2) { found_b[0] = base + 2; found_b[1] = pe2; }
            if (pe3 < rem_b && rem_b <= pe3 + c3) { found_b[0] = base + 3; found_b[1] = pe3; }
        }
        __syncthreads();
        pfx_t |= ((unsigned)found_t[0]) << shift;
        rem_t -= found_t[1];
        pfx_b |= ((unsigned)found_b[0]) << shift;
        rem_b -= found_b[1];
        msk |= 0xFFu << shift;
    }
    const unsigned t_top = pfx_t;  // exact K-th largest key
    const unsigned t_bot = pfx_b;  // exact K-th smallest key

    if (tid < 8) cnts[tid] = 0;
    __syncthreads();

    // ---- pass 3: count strict-side elements ----
    int my_gt = 0, my_lt = 0;
    #pragma unroll
    for (int c = 0; c < 4; c++) {
        unsigned kk = mykeys[c];
        my_gt += (kk > t_top);
        my_lt += (kk < t_bot);
    }
    if (my_gt) atomicAdd(&cnts[0], my_gt);
    if (my_lt) atomicAdd(&cnts[1], my_lt);
    __syncthreads();
    const int c1t = cnts[0];
    const int c1b = cnts[1];

    // ---- pass 4: gather top-k / bottom-k (exact, tie-aware; payload from regs) ----
    float* s_top = ws + OFF_STOP + b * K;
    float* w_top = ws + OFF_WTOP + b * K;
    float* s_bot = ws + OFF_SBOT + b * K;
    float* w_bot = ws + OFF_WBOT + b * K;
    float swt = 0.f, swb = 0.f;
    #pragma unroll
    for (int c = 0; c < 4; c++) {
        unsigned kk = mykeys[c];
        if (kk > t_top) {
            int pos = atomicAdd(&cnts[2], 1);
            s_top[pos] = mysc[c]; w_top[pos] = mysw[c]; swt += mysw[c];
        } else if (kk == t_top) {
            int tt = atomicAdd(&cnts[3], 1);
            if (tt < K - c1t) {
                int pos = c1t + tt;
                s_top[pos] = mysc[c]; w_top[pos] = mysw[c]; swt += mysw[c];
            }
        }
        if (kk < t_bot) {
            int pos = atomicAdd(&cnts[4], 1);
            s_bot[pos] = mysc[c]; w_bot[pos] = mysw[c]; swb += mysw[c];
        } else if (kk == t_bot) {
            int tt = atomicAdd(&cnts[5], 1);
            if (tt < K - c1b) {
                int pos = c1b + tt;
                s_bot[pos] = mysc[c]; w_bot[pos] = mysw[c]; swb += mysw[c];
            }
        }
    }
    #pragma unroll
    for (int o = 32; o > 0; o >>= 1) {
        swt += __shfl_down(swt, o, 64);
        swb += __shfl_down(swb, o, 64);
    }
    __syncthreads();
    {
        int wv = tid >> 6;
        if ((tid & 63) == 0) { red[wv] = swt; red[16 + wv] = swb; }
    }
    __syncthreads();
    if (tid == 0) {
        float a = 0.f, bb = 0.f;
        for (int w = 0; w < 16; w++) { a += red[w]; bb += red[16 + w]; }
        ws[OFF_SWT + b] = a;
        ws[OFF_SWB + b] = bb;
    }
}

// Pairwise softplus reduction. grid = (B, 2 i-tiles, 4 j-chunks), block = 256.
// Each thread handles TWO i-rows against the shared j-tile (ILP=8, half the
// LDS traffic of one-row-per-thread).
__global__ __launch_bounds__(256) void k_pair(float* __restrict__ ws)
{
    __shared__ __align__(16) float sb[208];
    __shared__ __align__(16) float wb[208];
    __shared__ float red2[4];

    const int b = blockIdx.x;
    const int it = blockIdx.y;   // i tile (512 rows per tile)
    const int z  = blockIdx.z;   // j chunk
    const int tid = threadIdx.x;

    const float* s_top = ws + OFF_STOP + b * K;
    const float* w_top = ws + OFF_WTOP + b * K;
    const float* s_bot = ws + OFF_SBOT + b * K;
    const float* w_bot = ws + OFF_WBOT + b * K;

    const int jbase = z * 205;
    const int jlen  = (z == 3) ? (K - 3 * 205) : 205;   // 204 for z==3

    for (int jj = tid; jj < 208; jj += 256) {
        if (jj < jlen) { sb[jj] = s_bot[jbase + jj]; wb[jj] = w_bot[jbase + jj]; }
        else           { sb[jj] = 0.f;               wb[jj] = 0.f; }
    }
    __syncthreads();

    const int i0 = it * 512 + tid;
    const int i1 = i0 + 256;
    const bool v0 = (i0 < K), v1 = (i1 < K);
    const float si0 = v0 ? s_top[i0] : 0.f;
    const float wi0 = v0 ? w_top[i0] : 0.f;
    const float si1 = v1 ? s_top[i1] : 0.f;
    const float wi1 = v1 ? w_top[i1] : 0.f;

    float acc0 = 0.f, acc1 = 0.f;
    const float4* sv = (const float4*)sb;
    const float4* wv = (const float4*)wb;
    for (int q = 0; q < 52; q++) {
        float4 s4 = sv[q];
        float4 w4 = wv[q];
        acc0 = fmaf(softplusf(s4.x - si0), w4.x, acc0);
        acc1 = fmaf(softplusf(s4.x - si1), w4.x, acc1);
        acc0 = fmaf(softplusf(s4.y - si0), w4.y, acc0);
        acc1 = fmaf(softplusf(s4.y - si1), w4.y, acc1);
        acc0 = fmaf(softplusf(s4.z - si0), w4.z, acc0);
        acc1 = fmaf(softplusf(s4.z - si1), w4.z, acc1);
        acc0 = fmaf(softplusf(s4.w - si0), w4.w, acc0);
        acc1 = fmaf(softplusf(s4.w - si1), w4.w, acc1);
    }
    float contrib = acc0 * wi0 + acc1 * wi1;

    #pragma unroll
    for (int o = 32; o > 0; o >>= 1) contrib += __shfl_down(contrib, o, 64);
    if ((tid & 63) == 0) red2[tid >> 6] = contrib;
    __syncthreads();
    if (tid == 0) {
        float tot = red2[0] + red2[1] + red2[2] + red2[3];
        atomicAdd(&ws[OFF_RNUM + b], tot);
    }
}

// Finalize: one wave handles all 64 batches.
__global__ __launch_bounds__(64) void k_final(const float* __restrict__ ws,
                                              float* __restrict__ out)
{
    const int t = threadIdx.x;  // 0..63 == batch
    float rn  = ws[OFF_RNUM + t];
    float st  = ws[OFF_SWT  + t];
    float sbm = ws[OFF_SWB  + t];
    float lr  = rn / (st * sbm + EPSF);

    float wsum = ws[OFF_TWS  + t];
    float pbt  = ws[OFF_TNUM + t] / (wsum + EPSF);
    float vld  = (wsum > 0.f) ? 1.f : 0.f;
    float vtr  = vld * pbt;
    float ps   = ws[OFF_PSUM + t];

    #pragma unroll
    for (int o = 32; o > 0; o >>= 1) {
        lr  += __shfl_down(lr,  o, 64);
        vtr += __shfl_down(vtr, o, 64);
        vld += __shfl_down(vld, o, 64);
        ps  += __shfl_down(ps,  o, 64);
    }
    if (t == 0) {
        float avg_rank  = lr / (float)B;
        float nv        = fmaxf(vld, 1.f);
        float avg_trade = vtr / nv;
        float mean_p    = ps / (float)(B * N);
        out[0] = avg_rank + TRADE_LAMBDA * avg_trade;
        out[1] = avg_rank;
        out[2] = avg_trade;
        out[3] = mean_p;
    }
}

extern "C" void kernel_launch(void* const* d_in, const int* in_sizes, int n_in,
                              void* d_out, int out_size, void* d_ws, size_t ws_size,
                              hipStream_t stream) {
    const float* scores  = (const float*)d_in[0];
    const float* p_trade = (const float*)d_in[1];
    const float* y_rank  = (const float*)d_in[2];
    const float* y_trade = (const float*)d_in[3];
    const float* weights = (const float*)d_in[4];
    const float* mask    = (const float*)d_in[5];
    float* ws  = (float*)d_ws;
    float* out = (float*)d_out;

    hipLaunchKernelGGL(k_select_trade, dim3(128), dim3(1024), 0, stream,
                       scores, p_trade, y_rank, y_trade, weights, mask, ws);
    hipLaunchKernelGGL(k_pair, dim3(B, 2, 4), dim3(256), 0, stream, ws);
    hipLaunchKernelGGL(k_final, dim3(1), dim3(64), 0, stream, ws, out);
}